// Round 8
// baseline (669.731 us; speedup 1.0000x reference)
//
#include <hip/hip_runtime.h>

#define N_ORB 256
#define N_F   64
#define HID   128

__device__ __forceinline__ float readlane_f(float x, int l) {
    return __int_as_float(__builtin_amdgcn_readlane(__float_as_int(x), l));
}

// wave64 max-reduce via DPP (row_shr 1/2/4/8, row_bcast 15/31); result in lane 63.
__device__ __forceinline__ unsigned wave_max_u32(unsigned v) {
    unsigned t;
    t = (unsigned)__builtin_amdgcn_update_dpp((int)v, (int)v, 0x111, 0xF, 0xF, false); v = v > t ? v : t;
    t = (unsigned)__builtin_amdgcn_update_dpp((int)v, (int)v, 0x112, 0xF, 0xF, false); v = v > t ? v : t;
    t = (unsigned)__builtin_amdgcn_update_dpp((int)v, (int)v, 0x114, 0xF, 0xF, false); v = v > t ? v : t;
    t = (unsigned)__builtin_amdgcn_update_dpp((int)v, (int)v, 0x118, 0xF, 0xF, false); v = v > t ? v : t;
    t = (unsigned)__builtin_amdgcn_update_dpp((int)v, (int)v, 0x142, 0xF, 0xF, false); v = v > t ? v : t;
    t = (unsigned)__builtin_amdgcn_update_dpp((int)v, (int)v, 0x143, 0xF, 0xF, false); v = v > t ? v : t;
    return v;
}

__global__ __launch_bounds__(256)
__attribute__((amdgpu_waves_per_eu(4, 4)))   // pin: 512/4 = 128-reg budget, no AGPR-spill incentive
void njs_kernel(
    const float* __restrict__ nmat,
    const float* __restrict__ M,
    const float* __restrict__ W,
    const float* __restrict__ bvec,
    float* __restrict__ out,
    int write_complex)
{
    const int lane = threadIdx.x & 63;
    const int wid  = threadIdx.x >> 6;
    const int row  = blockIdx.x * 4 + wid;   // one sample per wave
    __shared__ int idx_lds[4][N_F];

    // ---- 1. occupied orbitals (ascending), rank via ballots ----
    const float4 nv = *reinterpret_cast<const float4*>(nmat + (size_t)row * N_ORB + lane * 4);
    unsigned bits = (nv.x > 0.5f ? 1u : 0u) | (nv.y > 0.5f ? 2u : 0u) |
                    (nv.z > 0.5f ? 4u : 0u) | (nv.w > 0.5f ? 8u : 0u);
    unsigned long long bal0 = __ballot(bits & 1u);
    unsigned long long bal1 = __ballot(bits & 2u);
    unsigned long long bal2 = __ballot(bits & 4u);
    unsigned long long bal3 = __ballot(bits & 8u);
    const unsigned long long below = (1ull << lane) - 1ull;
    int r = __popcll(bal0 & below) + __popcll(bal1 & below) +
            __popcll(bal2 & below) + __popcll(bal3 & below);
    #pragma unroll
    for (int c = 0; c < 4; ++c) {
        if (bits & (1u << c)) {
            idx_lds[wid][r] = lane * 4 + c;
            ++r;
        }
    }
    __syncthreads();
    const int o = idx_lds[wid][lane];   // orbital index of fermion `lane`

    // ---- 2. load my Slater row: A[lane][:] = M[o][:] ----
    float a[N_F];
    {
        const float* Mr = M + (size_t)o * N_F;
        #pragma unroll
        for (int j = 0; j < N_F; j += 4) {
            const float4 v = *reinterpret_cast<const float4*>(Mr + j);
            a[j] = v.x; a[j+1] = v.y; a[j+2] = v.z; a[j+3] = v.w;
        }
    }

    // ---- 3. f32 LU, partial pivoting, rolled k-loop ----
    // Dead-column updates (j<=k in alive chunks) are harmless: used rows /
    // dead columns are never read again; pivot search masks used lanes.
    unsigned long long used = 0ull;
    int   expsum = 0;      // sum of biased exponents of |pivot|
    float vprod  = 1.0f;   // product of pivot mantissas in [1,2); <= 2^64
    int   neg    = 0;      // parity: negative pivots ^ permutation inversions
    float acur   = a[0];   // tracks a[k] per lane (k is runtime)

    #pragma unroll 1
    for (int k = 0; k < N_F; ++k) {
        // packed argmax key: |acur| bits with low 6 bits replaced by lane id
        const unsigned mykey = (((unsigned)__float_as_int(fabsf(acur))) & ~63u) | (unsigned)lane;
        const unsigned key   = ((used >> lane) & 1ull) ? 0u : mykey;
        const unsigned kmax  = wave_max_u32(key);
        const int ps   = __builtin_amdgcn_readlane((int)kmax, 63) & 63;
        const int ipiv = __builtin_amdgcn_readlane(__float_as_int(acur), ps);

        expsum += (ipiv >> 23) & 0xFF;                 // biased exponent (SALU)
        neg    ^= (int)(((unsigned)ipiv) >> 31);       // sign bit (SALU)
        vprod  *= __int_as_float((ipiv & 0x7FFFFF) | 0x3F800000);

        const unsigned long long belowp = (1ull << ps) - 1ull;
        neg ^= (int)((__popcll(used) - __popcll(used & belowp)) & 1);
        used |= (1ull << ps);

        // reciprocal + one Newton step: rel err ~2^-44
        const float piv = __int_as_float(ipiv);
        float rp = __builtin_amdgcn_rcpf(piv);
        rp = rp * fmaf(-piv, rp, 2.0f);
        const float mult = acur * rp;                  // garbage on used rows: harmless

        float anext = 0.0f;
        #pragma unroll
        for (int c = 0; c < 4; ++c) {
            if (16 * c + 15 > k) {                     // wave-uniform chunk skip
                #pragma unroll
                for (int jj = 0; jj < 16; ++jj) {
                    const int j = 16 * c + jj;         // static register index
                    a[j] = fmaf(-mult, readlane_f(a[j], ps), a[j]);
                    if (j == k + 1) anext = a[j];      // uniform cond, static idx
                }
            }
        }
        acur = anext;
    }
    const float ld2 = (float)(expsum - 64 * 127) + __log2f(vprod);

    // ---- 4. Jastrow (f32): y = sum occupied rows of W; J = sum tanh(y+b) ----
    float y0 = 0.0f, y1 = 0.0f;
    #pragma unroll 8
    for (int i = 0; i < N_F; ++i) {
        const int os = __builtin_amdgcn_readlane(o, i);
        const float2 w = *reinterpret_cast<const float2*>(W + (size_t)os * HID + lane * 2);
        y0 += w.x; y1 += w.y;
    }
    y0 += bvec[lane * 2];
    y1 += bvec[lane * 2 + 1];
    float t = tanhf(y0) + tanhf(y1);
    #pragma unroll
    for (int d = 32; d >= 1; d >>= 1) t += __shfl_xor(t, d);

    // ---- 5. write result ----
    if (lane == 0) {
        const float real = ld2 * 0.6931471805599453f + t;
        if (write_complex) {
            out[(size_t)row * 2]     = real;
            out[(size_t)row * 2 + 1] = (neg & 1) ? 3.14159265358979323846f : 0.0f;
        } else {
            out[row] = real;   // harness compares the complex64 real part as f32
        }
    }
}

extern "C" void kernel_launch(void* const* d_in, const int* in_sizes, int n_in,
                              void* d_out, int out_size, void* d_ws, size_t ws_size,
                              hipStream_t stream) {
    const float* nmat = (const float*)d_in[0];
    const float* M    = (const float*)d_in[1];
    const float* W    = (const float*)d_in[2];
    const float* b    = (const float*)d_in[3];
    float* out = (float*)d_out;
    const int B = in_sizes[0] / N_ORB;
    const int write_complex = (out_size >= 2 * B) ? 1 : 0;
    njs_kernel<<<B / 4, 256, 0, stream>>>(nmat, M, W, b, out, write_complex);
}

// Round 9
// 443.781 us; speedup vs baseline: 1.5091x; 1.5091x over previous
//
#include <hip/hip_runtime.h>

#define N_ORB 256
#define N_F   64
#define HID   128
#define NLDS  16   // columns 0..15 live in LDS during phase A (die by step 16)
#define LP    17   // LDS row pitch in floats; odd => conflict-free column reads

__device__ __forceinline__ float readlane_f(float x, int l) {
    return __int_as_float(__builtin_amdgcn_readlane(__float_as_int(x), l));
}

// wave64 max-reduce via DPP (row_shr 1/2/4/8, row_bcast 15/31); result in lane 63.
__device__ __forceinline__ unsigned wave_max_u32(unsigned v) {
    unsigned t;
    t = (unsigned)__builtin_amdgcn_update_dpp((int)v, (int)v, 0x111, 0xF, 0xF, false); v = v > t ? v : t;
    t = (unsigned)__builtin_amdgcn_update_dpp((int)v, (int)v, 0x112, 0xF, 0xF, false); v = v > t ? v : t;
    t = (unsigned)__builtin_amdgcn_update_dpp((int)v, (int)v, 0x114, 0xF, 0xF, false); v = v > t ? v : t;
    t = (unsigned)__builtin_amdgcn_update_dpp((int)v, (int)v, 0x118, 0xF, 0xF, false); v = v > t ? v : t;
    t = (unsigned)__builtin_amdgcn_update_dpp((int)v, (int)v, 0x142, 0xF, 0xF, false); v = v > t ? v : t;
    t = (unsigned)__builtin_amdgcn_update_dpp((int)v, (int)v, 0x143, 0xF, 0xF, false); v = v > t ? v : t;
    return v;
}

__global__ __launch_bounds__(256)
__attribute__((amdgpu_waves_per_eu(6, 8)))
void njs_kernel(
    const float* __restrict__ nmat,
    const float* __restrict__ M,
    const float* __restrict__ W,
    const float* __restrict__ bvec,
    float* __restrict__ out,
    int write_complex)
{
    const int lane = threadIdx.x & 63;
    const int wid  = threadIdx.x >> 6;
    const int row  = blockIdx.x * 4 + wid;   // one sample per wave

    __shared__ int   idx_lds[4][N_F];
    __shared__ float Acol[4][N_F * LP];      // per-wave private 64x16 (pitch 17)

    // ---- 1. occupied orbitals (ascending), rank via ballots ----
    const float4 nv = *reinterpret_cast<const float4*>(nmat + (size_t)row * N_ORB + lane * 4);
    unsigned bits = (nv.x > 0.5f ? 1u : 0u) | (nv.y > 0.5f ? 2u : 0u) |
                    (nv.z > 0.5f ? 4u : 0u) | (nv.w > 0.5f ? 8u : 0u);
    unsigned long long bal0 = __ballot(bits & 1u);
    unsigned long long bal1 = __ballot(bits & 2u);
    unsigned long long bal2 = __ballot(bits & 4u);
    unsigned long long bal3 = __ballot(bits & 8u);
    const unsigned long long below = (1ull << lane) - 1ull;
    int r = __popcll(bal0 & below) + __popcll(bal1 & below) +
            __popcll(bal2 & below) + __popcll(bal3 & below);
    #pragma unroll
    for (int c = 0; c < 4; ++c) {
        if (bits & (1u << c)) {
            idx_lds[wid][r] = lane * 4 + c;
            ++r;
        }
    }
    __syncthreads();
    const int o = idx_lds[wid][lane];   // orbital index of fermion `lane`

    // ---- 2. load row: cols 0..15 -> LDS, cols 16..63 -> regs a[0..47] ----
    float a[N_F - NLDS];
    const float* Mr = M + (size_t)o * N_F;
    float* Al = &Acol[wid][lane * LP];       // my row in LDS
    #pragma unroll
    for (int j = 0; j < NLDS; j += 4) {
        const float4 v = *reinterpret_cast<const float4*>(Mr + j);
        Al[j] = v.x; Al[j+1] = v.y; Al[j+2] = v.z; Al[j+3] = v.w;
    }
    #pragma unroll
    for (int s = 0; s < N_F - NLDS; s += 4) {
        const float4 v = *reinterpret_cast<const float4*>(Mr + NLDS + s);
        a[s] = v.x; a[s+1] = v.y; a[s+2] = v.z; a[s+3] = v.w;
    }
    asm volatile("s_waitcnt lgkmcnt(0)" ::: "memory");   // LDS init visible wave-wide

    unsigned long long used = 0ull;
    int   expsum = 0;      // sum of biased exponents of |pivot|
    float vprod  = 1.0f;   // product of pivot mantissas in [1,2); <= 2^64
    int   neg    = 0;      // parity: negative pivots ^ permutation inversions

    // ---- 3a. Phase A: k = 0..15 — pivot column in LDS (runtime k OK) ----
    #pragma unroll 1
    for (int k = 0; k < NLDS; ++k) {
        const float myAk = Al[k];
        const unsigned mykey = (((unsigned)__float_as_int(fabsf(myAk))) & ~63u) | (unsigned)lane;
        const unsigned key   = ((used >> lane) & 1ull) ? 0u : mykey;
        const int ps   = __builtin_amdgcn_readlane((int)wave_max_u32(key), 63) & 63;
        const int ipiv = __builtin_amdgcn_readlane(__float_as_int(myAk), ps);

        expsum += (ipiv >> 23) & 0xFF;
        neg    ^= (int)(((unsigned)ipiv) >> 31);
        vprod  *= __int_as_float((ipiv & 0x7FFFFF) | 0x3F800000);
        const unsigned long long belowp = (1ull << ps) - 1ull;
        neg ^= (int)((__popcll(used) - __popcll(used & belowp)) & 1);
        used |= (1ull << ps);

        const float piv = __int_as_float(ipiv);
        float rp = __builtin_amdgcn_rcpf(piv);
        rp = rp * fmaf(-piv, rp, 2.0f);            // Newton: rel err ~2^-44
        const float mult = myAk * rp;              // garbage on used rows: harmless

        const float* Ap = &Acol[wid][ps * LP];     // pivot row (broadcast reads)
        #pragma unroll 1
        for (int j = k + 1; j < NLDS; ++j)
            Al[j] = fmaf(-mult, Ap[j], Al[j]);
        #pragma unroll
        for (int s = 0; s < N_F - NLDS; ++s)       // all reg cols have j=16+s > k
            a[s] = fmaf(-mult, readlane_f(a[s], ps), a[s]);
    }

    // ---- 3b. Phase B: k = 16..63 — static pivot index, triangular, unrolled ----
    #pragma unroll
    for (int k = NLDS; k < N_F; ++k) {
        const int   s0  = k - NLDS;
        const float cur = a[s0];                   // static register index
        const unsigned mykey = (((unsigned)__float_as_int(fabsf(cur))) & ~63u) | (unsigned)lane;
        const unsigned key   = ((used >> lane) & 1ull) ? 0u : mykey;
        const int ps   = __builtin_amdgcn_readlane((int)wave_max_u32(key), 63) & 63;
        const int ipiv = __builtin_amdgcn_readlane(__float_as_int(cur), ps);

        expsum += (ipiv >> 23) & 0xFF;
        neg    ^= (int)(((unsigned)ipiv) >> 31);
        vprod  *= __int_as_float((ipiv & 0x7FFFFF) | 0x3F800000);
        const unsigned long long belowp = (1ull << ps) - 1ull;
        neg ^= (int)((__popcll(used) - __popcll(used & belowp)) & 1);
        used |= (1ull << ps);

        const float piv = __int_as_float(ipiv);
        float rp = __builtin_amdgcn_rcpf(piv);
        rp = rp * fmaf(-piv, rp, 2.0f);
        const float mult = cur * rp;

        #pragma unroll
        for (int s = s0 + 1; s < N_F - NLDS; ++s)  // triangular: j > k only
            a[s] = fmaf(-mult, readlane_f(a[s], ps), a[s]);
    }
    const float ld2 = (float)(expsum - 64 * 127) + __log2f(vprod);

    // ---- 4. Jastrow (f32): y = sum occupied rows of W; J = sum tanh(y+b) ----
    float y0 = 0.0f, y1 = 0.0f;
    #pragma unroll 8
    for (int i = 0; i < N_F; ++i) {
        const int os = __builtin_amdgcn_readlane(o, i);
        const float2 w = *reinterpret_cast<const float2*>(W + (size_t)os * HID + lane * 2);
        y0 += w.x; y1 += w.y;
    }
    y0 += bvec[lane * 2];
    y1 += bvec[lane * 2 + 1];
    float t = tanhf(y0) + tanhf(y1);
    #pragma unroll
    for (int d = 32; d >= 1; d >>= 1) t += __shfl_xor(t, d);

    // ---- 5. write result ----
    if (lane == 0) {
        const float real = ld2 * 0.6931471805599453f + t;
        if (write_complex) {
            out[(size_t)row * 2]     = real;
            out[(size_t)row * 2 + 1] = (neg & 1) ? 3.14159265358979323846f : 0.0f;
        } else {
            out[row] = real;   // harness compares the complex64 real part as f32
        }
    }
}

extern "C" void kernel_launch(void* const* d_in, const int* in_sizes, int n_in,
                              void* d_out, int out_size, void* d_ws, size_t ws_size,
                              hipStream_t stream) {
    const float* nmat = (const float*)d_in[0];
    const float* M    = (const float*)d_in[1];
    const float* W    = (const float*)d_in[2];
    const float* b    = (const float*)d_in[3];
    float* out = (float*)d_out;
    const int B = in_sizes[0] / N_ORB;
    const int write_complex = (out_size >= 2 * B) ? 1 : 0;
    njs_kernel<<<B / 4, 256, 0, stream>>>(nmat, M, W, b, out, write_complex);
}

// Round 10
// 442.148 us; speedup vs baseline: 1.5147x; 1.0037x over previous
//
#include <hip/hip_runtime.h>

#define N_ORB 256
#define N_F   64
#define HID   128
#define NLDS  16   // columns 0..15 live in LDS during phase A (die by step 16)
#define LP    17   // LDS row pitch in floats; odd => conflict-free column reads

__device__ __forceinline__ float readlane_f(float x, int l) {
    return __int_as_float(__builtin_amdgcn_readlane(__float_as_int(x), l));
}

// wave64 max-reduce via DPP (row_shr 1/2/4/8, row_bcast 15/31); result in lane 63.
__device__ __forceinline__ unsigned wave_max_u32(unsigned v) {
    unsigned t;
    t = (unsigned)__builtin_amdgcn_update_dpp((int)v, (int)v, 0x111, 0xF, 0xF, false); v = v > t ? v : t;
    t = (unsigned)__builtin_amdgcn_update_dpp((int)v, (int)v, 0x112, 0xF, 0xF, false); v = v > t ? v : t;
    t = (unsigned)__builtin_amdgcn_update_dpp((int)v, (int)v, 0x114, 0xF, 0xF, false); v = v > t ? v : t;
    t = (unsigned)__builtin_amdgcn_update_dpp((int)v, (int)v, 0x118, 0xF, 0xF, false); v = v > t ? v : t;
    t = (unsigned)__builtin_amdgcn_update_dpp((int)v, (int)v, 0x142, 0xF, 0xF, false); v = v > t ? v : t;
    t = (unsigned)__builtin_amdgcn_update_dpp((int)v, (int)v, 0x143, 0xF, 0xF, false); v = v > t ? v : t;
    return v;
}

// 1-wave workgroups, NO occupancy attributes: the only config observed to give
// natural (non-AGPR) allocation (R3: VGPR=72 zero-spill vs R4-R9 bs=256 always
// pinned <=64 arch VGPRs + accvgpr copy tax).
__global__ __launch_bounds__(64) void njs_kernel(
    const float* __restrict__ nmat,
    const float* __restrict__ M,
    const float* __restrict__ W,
    const float* __restrict__ bvec,
    float* __restrict__ out,
    int write_complex)
{
    const int lane = threadIdx.x;
    const int row  = blockIdx.x;   // one sample per wave/block

    __shared__ int   idx_lds[N_F];
    __shared__ float Acol[N_F * LP];      // 64 rows x 16 cols (pitch 17)

    // ---- 1. occupied orbitals (ascending), rank via ballots ----
    const float4 nv = *reinterpret_cast<const float4*>(nmat + (size_t)row * N_ORB + lane * 4);
    unsigned bits = (nv.x > 0.5f ? 1u : 0u) | (nv.y > 0.5f ? 2u : 0u) |
                    (nv.z > 0.5f ? 4u : 0u) | (nv.w > 0.5f ? 8u : 0u);
    unsigned long long bal0 = __ballot(bits & 1u);
    unsigned long long bal1 = __ballot(bits & 2u);
    unsigned long long bal2 = __ballot(bits & 4u);
    unsigned long long bal3 = __ballot(bits & 8u);
    const unsigned long long below = (1ull << lane) - 1ull;
    int r = __popcll(bal0 & below) + __popcll(bal1 & below) +
            __popcll(bal2 & below) + __popcll(bal3 & below);
    #pragma unroll
    for (int c = 0; c < 4; ++c) {
        if (bits & (1u << c)) {
            idx_lds[r] = lane * 4 + c;
            ++r;
        }
    }
    __syncthreads();
    const int o = idx_lds[lane];   // orbital index of fermion `lane`

    // ---- 2. load row: cols 0..15 -> LDS, cols 16..63 -> regs a[0..47] ----
    float a[N_F - NLDS];
    const float* Mr = M + (size_t)o * N_F;
    float* Al = &Acol[lane * LP];         // my row in LDS
    #pragma unroll
    for (int j = 0; j < NLDS; j += 4) {
        const float4 v = *reinterpret_cast<const float4*>(Mr + j);
        Al[j] = v.x; Al[j+1] = v.y; Al[j+2] = v.z; Al[j+3] = v.w;
    }
    #pragma unroll
    for (int s = 0; s < N_F - NLDS; s += 4) {
        const float4 v = *reinterpret_cast<const float4*>(Mr + NLDS + s);
        a[s] = v.x; a[s+1] = v.y; a[s+2] = v.z; a[s+3] = v.w;
    }
    asm volatile("s_waitcnt lgkmcnt(0)" ::: "memory");   // LDS init visible wave-wide

    unsigned long long used = 0ull;
    int   expsum = 0;      // sum of biased exponents of |pivot|
    float vprod  = 1.0f;   // product of pivot mantissas in [1,2); <= 2^64
    int   neg    = 0;      // parity: negative pivots ^ permutation inversions

    // ---- 3a. Phase A: k = 0..15 — pivot column in LDS (runtime k OK) ----
    #pragma unroll 1
    for (int k = 0; k < NLDS; ++k) {
        const float myAk = Al[k];
        const unsigned mykey = (((unsigned)__float_as_int(fabsf(myAk))) & ~63u) | (unsigned)lane;
        const unsigned key   = ((used >> lane) & 1ull) ? 0u : mykey;
        const int ps   = __builtin_amdgcn_readlane((int)wave_max_u32(key), 63) & 63;
        const int ipiv = __builtin_amdgcn_readlane(__float_as_int(myAk), ps);

        expsum += (ipiv >> 23) & 0xFF;
        neg    ^= (int)(((unsigned)ipiv) >> 31);
        vprod  *= __int_as_float((ipiv & 0x7FFFFF) | 0x3F800000);
        const unsigned long long belowp = (1ull << ps) - 1ull;
        neg ^= (int)((__popcll(used) - __popcll(used & belowp)) & 1);
        used |= (1ull << ps);

        const float piv = __int_as_float(ipiv);
        float rp = __builtin_amdgcn_rcpf(piv);
        rp = rp * fmaf(-piv, rp, 2.0f);            // Newton: rel err ~2^-44
        const float mult = myAk * rp;              // garbage on used rows: harmless

        const float* Ap = &Acol[ps * LP];          // pivot row (broadcast reads)
        #pragma unroll 1
        for (int j = k + 1; j < NLDS; ++j)
            Al[j] = fmaf(-mult, Ap[j], Al[j]);
        #pragma unroll
        for (int s = 0; s < N_F - NLDS; ++s)       // all reg cols have j=16+s > k
            a[s] = fmaf(-mult, readlane_f(a[s], ps), a[s]);
    }

    // ---- 3b. Phase B: k = 16..63 — static pivot index, triangular, unrolled ----
    #pragma unroll
    for (int k = NLDS; k < N_F; ++k) {
        const int   s0  = k - NLDS;
        const float cur = a[s0];                   // static register index
        const unsigned mykey = (((unsigned)__float_as_int(fabsf(cur))) & ~63u) | (unsigned)lane;
        const unsigned key   = ((used >> lane) & 1ull) ? 0u : mykey;
        const int ps   = __builtin_amdgcn_readlane((int)wave_max_u32(key), 63) & 63;
        const int ipiv = __builtin_amdgcn_readlane(__float_as_int(cur), ps);

        expsum += (ipiv >> 23) & 0xFF;
        neg    ^= (int)(((unsigned)ipiv) >> 31);
        vprod  *= __int_as_float((ipiv & 0x7FFFFF) | 0x3F800000);
        const unsigned long long belowp = (1ull << ps) - 1ull;
        neg ^= (int)((__popcll(used) - __popcll(used & belowp)) & 1);
        used |= (1ull << ps);

        const float piv = __int_as_float(ipiv);
        float rp = __builtin_amdgcn_rcpf(piv);
        rp = rp * fmaf(-piv, rp, 2.0f);
        const float mult = cur * rp;

        #pragma unroll
        for (int s = s0 + 1; s < N_F - NLDS; ++s)  // triangular: j > k only
            a[s] = fmaf(-mult, readlane_f(a[s], ps), a[s]);
    }
    const float ld2 = (float)(expsum - 64 * 127) + __log2f(vprod);

    // ---- 4. Jastrow (f32): y = sum occupied rows of W; J = sum tanh(y+b) ----
    float y0 = 0.0f, y1 = 0.0f;
    #pragma unroll 8
    for (int i = 0; i < N_F; ++i) {
        const int os = __builtin_amdgcn_readlane(o, i);
        const float2 w = *reinterpret_cast<const float2*>(W + (size_t)os * HID + lane * 2);
        y0 += w.x; y1 += w.y;
    }
    y0 += bvec[lane * 2];
    y1 += bvec[lane * 2 + 1];
    float t = tanhf(y0) + tanhf(y1);
    #pragma unroll
    for (int d = 32; d >= 1; d >>= 1) t += __shfl_xor(t, d);

    // ---- 5. write result ----
    if (lane == 0) {
        const float real = ld2 * 0.6931471805599453f + t;
        if (write_complex) {
            out[(size_t)row * 2]     = real;
            out[(size_t)row * 2 + 1] = (neg & 1) ? 3.14159265358979323846f : 0.0f;
        } else {
            out[row] = real;   // harness compares the complex64 real part as f32
        }
    }
}

extern "C" void kernel_launch(void* const* d_in, const int* in_sizes, int n_in,
                              void* d_out, int out_size, void* d_ws, size_t ws_size,
                              hipStream_t stream) {
    const float* nmat = (const float*)d_in[0];
    const float* M    = (const float*)d_in[1];
    const float* W    = (const float*)d_in[2];
    const float* b    = (const float*)d_in[3];
    float* out = (float*)d_out;
    const int B = in_sizes[0] / N_ORB;
    const int write_complex = (out_size >= 2 * B) ? 1 : 0;
    njs_kernel<<<B, 64, 0, stream>>>(nmat, M, W, b, out, write_complex);
}